// Round 4
// baseline (983.885 us; speedup 1.0000x reference)
//
#include <hip/hip_runtime.h>
#include <hip/hip_bf16.h>

// ---------------------------------------------------------------------------
// MainModalityDeformableMoE — analytic simplification:
//   Lq=Lk=1  =>  idx==0, sk==src, softmax-weights sum to 1  =>  attn = tile(src, NH)
//   => attn @ Wproj == src @ (sum of NH row-blocks of Wproj).  Woff/Watt dead.
// Pipeline: 3 relu-proj GEMMs -> gating fuse -> (Wproj-sum GEMM + resid) -> LN1
//           -> gelu GEMM -> GEMM + resid -> LN2 + head (sigmoid + cumprod).
// GEMMs: bf16 MFMA 16x16x32, 128x128 tile, BK=64, global_load_lds(16B) staging
// with XOR-swizzled global source so ds_read_b128 is bank-conflict-free.
// ---------------------------------------------------------------------------

#define B_ROWS 8192
#define HDIM 1024
#define F0 2048
#define F1 1024
#define F2 512
#define FFDIM 4096
#define NPRED 20

typedef __bf16 bf16x8 __attribute__((ext_vector_type(8)));
typedef float f32x4 __attribute__((ext_vector_type(4)));

__device__ __forceinline__ unsigned short f2bf(float f) {
    unsigned int u = __builtin_bit_cast(unsigned int, f);
    u += 0x7FFFu + ((u >> 16) & 1u);   // round-to-nearest-even
    return (unsigned short)(u >> 16);
}
__device__ __forceinline__ float bf2f(unsigned short s) {
    unsigned int u = ((unsigned int)s) << 16;
    return __builtin_bit_cast(float, u);
}
__device__ __forceinline__ unsigned int pack2(float lo, float hi) {
    return (unsigned int)f2bf(lo) | ((unsigned int)f2bf(hi) << 16);
}

// ---------------------------------------------------------------------------
// GEMM: out(MxN) = epi(A(MxK,bf16) @ Bt(NxK,bf16)^T + bias [+ resid])
// EPI: 0 = relu -> bf16 ; 1 = exact gelu -> bf16 ; 2 = +resid -> f32
// ---------------------------------------------------------------------------
template <int EPI>
__global__ __launch_bounds__(256) void gemm_bt(
    const unsigned short* __restrict__ A,
    const unsigned short* __restrict__ Bt,
    const float* __restrict__ bias,
    const float* __restrict__ resid,
    void* __restrict__ outp,
    int N, int K)
{
    __shared__ __attribute__((aligned(16))) unsigned short lsA[128 * 64];
    __shared__ __attribute__((aligned(16))) unsigned short lsB[128 * 64];
    const int t = threadIdx.x;
    const int lane = t & 63;
    const int wid = t >> 6;
    const int bn = blockIdx.x, bm = blockIdx.y;
    const int wr = wid >> 1, wc = wid & 1;

    f32x4 acc[4][4] = {};

    // Staging geometry: tile is 128 rows x 64 bf16 (128 B/row), linear in LDS.
    // LDS chunk c16 of row r holds global k-chunk (c16 ^ (r&7))  [XOR swizzle
    // applied on the GLOBAL source; LDS dest stays linear for global_load_lds].
    int rowj[4], scj[4];
#pragma unroll
    for (int j = 0; j < 4; ++j) {
        int o = j * 4096 + wid * 1024 + lane * 16;   // byte offset in tile
        int r = o >> 7;
        int c16 = (o >> 4) & 7;
        rowj[j] = r;
        scj[j] = c16 ^ (r & 7);
    }
    const unsigned short* Abase = A + (size_t)bm * 128 * K;
    const unsigned short* Bbase = Bt + (size_t)bn * 128 * K;

    const int ktiles = K >> 6;
    for (int kt = 0; kt < ktiles; ++kt) {
        const int k0 = kt * 64;
#pragma unroll
        for (int j = 0; j < 4; ++j) {
            const unsigned short* ga = Abase + (size_t)rowj[j] * K + k0 + scj[j] * 8;
            const unsigned short* gb = Bbase + (size_t)rowj[j] * K + k0 + scj[j] * 8;
            __builtin_amdgcn_global_load_lds(
                (const __attribute__((address_space(1))) unsigned int*)ga,
                (__attribute__((address_space(3))) unsigned int*)(lsA + j * 2048 + wid * 512),
                16, 0, 0);
            __builtin_amdgcn_global_load_lds(
                (const __attribute__((address_space(1))) unsigned int*)gb,
                (__attribute__((address_space(3))) unsigned int*)(lsB + j * 2048 + wid * 512),
                16, 0, 0);
        }
        __syncthreads();   // compiler drains vmcnt before s_barrier
#pragma unroll
        for (int ks = 0; ks < 2; ++ks) {
            bf16x8 af[4], bfr[4];
            const int kc = ks * 4 + (lane >> 4);
#pragma unroll
            for (int m = 0; m < 4; ++m) {
                int r = wr * 64 + m * 16 + (lane & 15);
                af[m] = *(const bf16x8*)(lsA + r * 64 + ((kc ^ (r & 7)) << 3));
            }
#pragma unroll
            for (int n = 0; n < 4; ++n) {
                int r = wc * 64 + n * 16 + (lane & 15);
                bfr[n] = *(const bf16x8*)(lsB + r * 64 + ((kc ^ (r & 7)) << 3));
            }
#pragma unroll
            for (int m = 0; m < 4; ++m)
#pragma unroll
                for (int n = 0; n < 4; ++n)
                    acc[m][n] = __builtin_amdgcn_mfma_f32_16x16x32_bf16(
                        af[m], bfr[n], acc[m][n], 0, 0, 0);
        }
        __syncthreads();
    }

    // Epilogue. C/D layout: col = lane&15, row = (lane>>4)*4 + reg.
#pragma unroll
    for (int n = 0; n < 4; ++n) {
        const int col = bn * 128 + wc * 64 + n * 16 + (lane & 15);
        const float bv = bias[col];
#pragma unroll
        for (int m = 0; m < 4; ++m) {
            const int row0 = bm * 128 + wr * 64 + m * 16 + ((lane >> 4) << 2);
#pragma unroll
            for (int r2 = 0; r2 < 4; ++r2) {
                const size_t idx = (size_t)(row0 + r2) * N + col;
                float v = acc[m][n][r2] + bv;
                if (EPI == 0) {
                    v = v > 0.f ? v : 0.f;
                    ((unsigned short*)outp)[idx] = f2bf(v);
                } else if (EPI == 1) {
                    float g = 0.5f * v * (1.f + erff(v * 0.70710678118654752f));
                    ((unsigned short*)outp)[idx] = f2bf(g);
                } else {
                    ((float*)outp)[idx] = v + resid[idx];
                }
            }
        }
    }
}

// ---------------------------------------------------------------------------
// Weight prep
// ---------------------------------------------------------------------------
template <int OUT_BF16>
__global__ void transpose_k(const float* __restrict__ in, void* __restrict__ out,
                            int R, int C)   // out[c*R + r] = in[r*C + c]
{
    __shared__ float tile[32][33];
    const int r0 = blockIdx.y * 32, c0 = blockIdx.x * 32;
    const int tx = threadIdx.x, ty = threadIdx.y;
#pragma unroll
    for (int i = 0; i < 4; ++i) {
        int r = r0 + ty + i * 8, c = c0 + tx;
        if (r < R && c < C) tile[ty + i * 8][tx] = in[(size_t)r * C + c];
    }
    __syncthreads();
#pragma unroll
    for (int i = 0; i < 4; ++i) {
        int c = c0 + ty + i * 8, r = r0 + tx;
        if (r < R && c < C) {
            float v = tile[tx][ty + i * 8];
            if (OUT_BF16) ((unsigned short*)out)[(size_t)c * R + r] = f2bf(v);
            else          ((float*)out)[(size_t)c * R + r] = v;
        }
    }
}

// WPT[n][k] = sum_h Wproj[h*H + k][n]   (1024x1024 bf16, transposed+summed)
__global__ void wproj_sum_k(const float* __restrict__ Wproj,
                            unsigned short* __restrict__ WPT)
{
    __shared__ float tile[32][33];
    const int k0 = blockIdx.y * 32, n0 = blockIdx.x * 32;
    const int tx = threadIdx.x, ty = threadIdx.y;
#pragma unroll
    for (int i = 0; i < 4; ++i) {
        int k = k0 + ty + i * 8, n = n0 + tx;
        float s = 0.f;
#pragma unroll
        for (int h = 0; h < 4; ++h) s += Wproj[(size_t)(h * HDIM + k) * HDIM + n];
        tile[ty + i * 8][tx] = s;
    }
    __syncthreads();
#pragma unroll
    for (int i = 0; i < 4; ++i) {
        int n = n0 + ty + i * 8, k = k0 + tx;
        WPT[(size_t)n * HDIM + k] = f2bf(tile[tx][ty + i * 8]);
    }
}

// ---------------------------------------------------------------------------
// Activation prep
// ---------------------------------------------------------------------------
__global__ void cvt_f32_bf16_k(const float* __restrict__ in,
                               unsigned short* __restrict__ out, int n8)
{
    for (int i = blockIdx.x * blockDim.x + threadIdx.x; i < n8;
         i += gridDim.x * blockDim.x) {
        const float4* p = (const float4*)(in + (size_t)i * 8);
        float4 a = p[0], b = p[1];
        uint4 o;
        o.x = pack2(a.x, a.y); o.y = pack2(a.z, a.w);
        o.z = pack2(b.x, b.y); o.w = pack2(b.z, b.w);
        *(uint4*)(out + (size_t)i * 8) = o;
    }
}

// x_m1 (B,8,1024) f32 -> mean over axis 1 -> bf16 (B,1024)
__global__ void mean8_k(const float* __restrict__ x, unsigned short* __restrict__ out,
                        int nq)
{
    for (int q = blockIdx.x * blockDim.x + threadIdx.x; q < nq;
         q += gridDim.x * blockDim.x) {
        int b = q >> 8, c4 = (q & 255) << 2;
        const float* base = x + (size_t)b * 8 * HDIM + c4;
        float4 s = {0.f, 0.f, 0.f, 0.f};
#pragma unroll
        for (int s8 = 0; s8 < 8; ++s8) {
            float4 v = *(const float4*)(base + s8 * HDIM);
            s.x += v.x; s.y += v.y; s.z += v.z; s.w += v.w;
        }
        uint2 o;
        o.x = pack2(s.x * 0.125f, s.y * 0.125f);
        o.y = pack2(s.z * 0.125f, s.w * 0.125f);
        *(uint2*)(out + (size_t)b * HDIM + c4) = o;
    }
}

// ---------------------------------------------------------------------------
// Gating: per-row (wave) softmax over 3 modality dots, then fuse.
// ---------------------------------------------------------------------------
__global__ __launch_bounds__(256) void gating_k(
    const unsigned short* __restrict__ r0p, const unsigned short* __restrict__ r1p,
    const unsigned short* __restrict__ r2p,
    const float* __restrict__ WgT,  // (3, 3072): WgT[j*3072 + m*1024 + e]
    const float* __restrict__ bg,
    unsigned short* __restrict__ fusedb, float* __restrict__ fusedf)
{
    const int row = blockIdx.x * 4 + (threadIdx.x >> 6);
    const int lane = threadIdx.x & 63;
    float rv[3][16];
    const unsigned short* rp[3] = {r0p, r1p, r2p};
#pragma unroll
    for (int m = 0; m < 3; ++m) {
        const uint4* p = (const uint4*)(rp[m] + (size_t)row * HDIM + lane * 16);
        uint4 u0 = p[0], u1 = p[1];
        unsigned int w[8] = {u0.x, u0.y, u0.z, u0.w, u1.x, u1.y, u1.z, u1.w};
#pragma unroll
        for (int q = 0; q < 8; ++q) {
            rv[m][q * 2]     = bf2f((unsigned short)(w[q] & 0xffffu));
            rv[m][q * 2 + 1] = bf2f((unsigned short)(w[q] >> 16));
        }
    }
    float s[3] = {0.f, 0.f, 0.f};
#pragma unroll
    for (int j = 0; j < 3; ++j) {
#pragma unroll
        for (int m = 0; m < 3; ++m) {
            const float* wp = WgT + j * 3072 + m * HDIM + lane * 16;
#pragma unroll
            for (int e = 0; e < 16; ++e) s[j] += rv[m][e] * wp[e];
        }
    }
#pragma unroll
    for (int j = 0; j < 3; ++j)
#pragma unroll
        for (int off = 32; off > 0; off >>= 1) s[j] += __shfl_xor(s[j], off);

    float s0 = s[0] + bg[0], s1 = s[1] + bg[1], s2 = s[2] + bg[2];
    float mx = fmaxf(s0, fmaxf(s1, s2));
    float e0 = expf(s0 - mx), e1 = expf(s1 - mx), e2 = expf(s2 - mx);
    float inv = 1.f / (e0 + e1 + e2);
    float g0 = e0 * inv, g1 = e1 * inv, g2 = e2 * inv;

    float f[16];
#pragma unroll
    for (int e = 0; e < 16; ++e)
        f[e] = g0 * rv[0][e] + g1 * rv[1][e] + g2 * rv[2][e];

    float4* ff = (float4*)(fusedf + (size_t)row * HDIM + lane * 16);
#pragma unroll
    for (int q = 0; q < 4; ++q) {
        float4 v = {f[q * 4], f[q * 4 + 1], f[q * 4 + 2], f[q * 4 + 3]};
        ff[q] = v;
    }
    uint4* fb = (uint4*)(fusedb + (size_t)row * HDIM + lane * 16);
    uint4 o0, o1;
    o0.x = pack2(f[0], f[1]);  o0.y = pack2(f[2], f[3]);
    o0.z = pack2(f[4], f[5]);  o0.w = pack2(f[6], f[7]);
    o1.x = pack2(f[8], f[9]);  o1.y = pack2(f[10], f[11]);
    o1.z = pack2(f[12], f[13]); o1.w = pack2(f[14], f[15]);
    fb[0] = o0; fb[1] = o1;
}

// ---------------------------------------------------------------------------
// LayerNorm (row per wave): y = (x-mu)*rsqrt(var+1e-5)*g + be -> bf16 + f32
// ---------------------------------------------------------------------------
__global__ __launch_bounds__(256) void ln_k(
    const float* __restrict__ z, const float* __restrict__ g,
    const float* __restrict__ be,
    unsigned short* __restrict__ yb, float* __restrict__ yf)
{
    const int row = blockIdx.x * 4 + (threadIdx.x >> 6);
    const int lane = threadIdx.x & 63;
    const float4* zp = (const float4*)(z + (size_t)row * HDIM + lane * 16);
    float x[16];
    float4 v0 = zp[0], v1 = zp[1], v2 = zp[2], v3 = zp[3];
    x[0]=v0.x; x[1]=v0.y; x[2]=v0.z; x[3]=v0.w;
    x[4]=v1.x; x[5]=v1.y; x[6]=v1.z; x[7]=v1.w;
    x[8]=v2.x; x[9]=v2.y; x[10]=v2.z; x[11]=v2.w;
    x[12]=v3.x; x[13]=v3.y; x[14]=v3.z; x[15]=v3.w;
    float sum = 0.f, sq = 0.f;
#pragma unroll
    for (int e = 0; e < 16; ++e) { sum += x[e]; sq += x[e] * x[e]; }
#pragma unroll
    for (int off = 32; off > 0; off >>= 1) {
        sum += __shfl_xor(sum, off);
        sq  += __shfl_xor(sq, off);
    }
    float mu = sum * (1.f / HDIM);
    float var = sq * (1.f / HDIM) - mu * mu;
    float rs = rsqrtf(var + 1e-5f);
    const float4* gp = (const float4*)(g + lane * 16);
    const float4* bp = (const float4*)(be + lane * 16);
    float y[16];
#pragma unroll
    for (int q = 0; q < 4; ++q) {
        float4 gv = gp[q], bv = bp[q];
        y[q*4+0] = (x[q*4+0] - mu) * rs * gv.x + bv.x;
        y[q*4+1] = (x[q*4+1] - mu) * rs * gv.y + bv.y;
        y[q*4+2] = (x[q*4+2] - mu) * rs * gv.z + bv.z;
        y[q*4+3] = (x[q*4+3] - mu) * rs * gv.w + bv.w;
    }
    float4* yfp = (float4*)(yf + (size_t)row * HDIM + lane * 16);
#pragma unroll
    for (int q = 0; q < 4; ++q) {
        float4 v = {y[q*4], y[q*4+1], y[q*4+2], y[q*4+3]};
        yfp[q] = v;
    }
    uint4* ybp = (uint4*)(yb + (size_t)row * HDIM + lane * 16);
    uint4 o0, o1;
    o0.x = pack2(y[0], y[1]);   o0.y = pack2(y[2], y[3]);
    o0.z = pack2(y[4], y[5]);   o0.w = pack2(y[6], y[7]);
    o1.x = pack2(y[8], y[9]);   o1.y = pack2(y[10], y[11]);
    o1.z = pack2(y[12], y[13]); o1.w = pack2(y[14], y[15]);
    ybp[0] = o0; ybp[1] = o1;
}

// ---------------------------------------------------------------------------
// LN2 + head: h = LN(z2); logits = h @ Wh + bh; hazards=sigmoid; survival=cumprod
// ---------------------------------------------------------------------------
__global__ __launch_bounds__(256) void head_k(
    const float* __restrict__ z, const float* __restrict__ g,
    const float* __restrict__ be,
    const float* __restrict__ WhT,  // (20,1024)
    const float* __restrict__ bh, float* __restrict__ out)
{
    const int row = blockIdx.x * 4 + (threadIdx.x >> 6);
    const int lane = threadIdx.x & 63;
    const float4* zp = (const float4*)(z + (size_t)row * HDIM + lane * 16);
    float x[16];
    float4 v0 = zp[0], v1 = zp[1], v2 = zp[2], v3 = zp[3];
    x[0]=v0.x; x[1]=v0.y; x[2]=v0.z; x[3]=v0.w;
    x[4]=v1.x; x[5]=v1.y; x[6]=v1.z; x[7]=v1.w;
    x[8]=v2.x; x[9]=v2.y; x[10]=v2.z; x[11]=v2.w;
    x[12]=v3.x; x[13]=v3.y; x[14]=v3.z; x[15]=v3.w;
    float sum = 0.f, sq = 0.f;
#pragma unroll
    for (int e = 0; e < 16; ++e) { sum += x[e]; sq += x[e] * x[e]; }
#pragma unroll
    for (int off = 32; off > 0; off >>= 1) {
        sum += __shfl_xor(sum, off);
        sq  += __shfl_xor(sq, off);
    }
    float mu = sum * (1.f / HDIM);
    float var = sq * (1.f / HDIM) - mu * mu;
    float rs = rsqrtf(var + 1e-5f);
    const float4* gp = (const float4*)(g + lane * 16);
    const float4* bp = (const float4*)(be + lane * 16);
    float h[16];
#pragma unroll
    for (int q = 0; q < 4; ++q) {
        float4 gv = gp[q], bv = bp[q];
        h[q*4+0] = (x[q*4+0] - mu) * rs * gv.x + bv.x;
        h[q*4+1] = (x[q*4+1] - mu) * rs * gv.y + bv.y;
        h[q*4+2] = (x[q*4+2] - mu) * rs * gv.z + bv.z;
        h[q*4+3] = (x[q*4+3] - mu) * rs * gv.w + bv.w;
    }
    float lg[NPRED];
#pragma unroll
    for (int j = 0; j < NPRED; ++j) {
        const float4* wp = (const float4*)(WhT + j * HDIM + lane * 16);
        float4 w0 = wp[0], w1 = wp[1], w2 = wp[2], w3 = wp[3];
        float d = h[0]*w0.x + h[1]*w0.y + h[2]*w0.z + h[3]*w0.w
                + h[4]*w1.x + h[5]*w1.y + h[6]*w1.z + h[7]*w1.w
                + h[8]*w2.x + h[9]*w2.y + h[10]*w2.z + h[11]*w2.w
                + h[12]*w3.x + h[13]*w3.y + h[14]*w3.z + h[15]*w3.w;
#pragma unroll
        for (int off = 32; off > 0; off >>= 1) d += __shfl_xor(d, off);
        lg[j] = d;
    }
    if (lane == 0) {
        float sv = 1.f;
#pragma unroll
        for (int j = 0; j < NPRED; ++j) {
            float l = lg[j] + bh[j];
            float hz = 1.f / (1.f + expf(-l));
            sv *= (1.f - hz);
            out[(size_t)row * NPRED + j] = hz;
            out[(size_t)B_ROWS * NPRED + (size_t)row * NPRED + j] = sv;
        }
    }
}

// ---------------------------------------------------------------------------
// Workspace layout (bytes). Aliases verified against kernel ordering.
// ---------------------------------------------------------------------------
constexpr size_t SZ_XB0   = (size_t)B_ROWS * F0 * 2;
constexpr size_t SZ_XB1M  = (size_t)B_ROWS * HDIM * 2;
constexpr size_t SZ_XB2   = (size_t)B_ROWS * F2 * 2;
constexpr size_t SZ_R     = (size_t)B_ROWS * HDIM * 2;
constexpr size_t SZ_F32H  = (size_t)B_ROWS * HDIM * 4;

constexpr size_t OFF_XB0   = 0;
constexpr size_t OFF_XB1M  = OFF_XB0 + SZ_XB0;
constexpr size_t OFF_XB2   = OFF_XB1M + SZ_XB1M;
constexpr size_t OFF_R0    = OFF_XB2 + SZ_XB2;
constexpr size_t OFF_R1    = OFF_R0 + SZ_R;
constexpr size_t OFF_R2    = OFF_R1 + SZ_R;
constexpr size_t OFF_FUSEB = OFF_R2 + SZ_R;
constexpr size_t OFF_FUSEF = OFF_FUSEB + SZ_R;
constexpr size_t OFF_Z2    = OFF_FUSEF + SZ_F32H;
constexpr size_t OFF_WT0   = OFF_Z2 + SZ_F32H;
constexpr size_t OFF_WT1   = OFF_WT0 + (size_t)HDIM * F0 * 2;
constexpr size_t OFF_WT2   = OFF_WT1 + (size_t)HDIM * F1 * 2;
constexpr size_t OFF_WPT   = OFF_WT2 + (size_t)HDIM * F2 * 2;
constexpr size_t OFF_W1T   = OFF_WPT + (size_t)HDIM * HDIM * 2;
constexpr size_t OFF_W2T   = OFF_W1T + (size_t)FFDIM * HDIM * 2;
constexpr size_t OFF_WGT   = OFF_W2T + (size_t)HDIM * FFDIM * 2;
constexpr size_t OFF_WHT   = OFF_WGT + (size_t)3 * 3072 * 4;
// Aliases (lifetimes disjoint):
constexpr size_t OFF_Z1   = OFF_XB0;    // 32MB f32, xb0 dead after GEMM1
constexpr size_t OFF_H1B  = OFF_XB1M;   // 16MB bf16, xb1m dead after GEMM2
constexpr size_t OFF_H1F  = OFF_R0;     // 32MB f32 spans R0+R1, dead after gating
constexpr size_t OFF_HMID = OFF_R2;     // 64MB bf16 spans R2+FUSEB+FUSEF

static inline void launch_gemm(int epi, const void* A, const void* Bt,
                               const float* bias, const float* resid, void* outp,
                               int M, int N, int K, hipStream_t s)
{
    dim3 grid(N / 128, M / 128), blk(256);
    if (epi == 0)
        gemm_bt<0><<<grid, blk, 0, s>>>((const unsigned short*)A,
            (const unsigned short*)Bt, bias, resid, outp, N, K);
    else if (epi == 1)
        gemm_bt<1><<<grid, blk, 0, s>>>((const unsigned short*)A,
            (const unsigned short*)Bt, bias, resid, outp, N, K);
    else
        gemm_bt<2><<<grid, blk, 0, s>>>((const unsigned short*)A,
            (const unsigned short*)Bt, bias, resid, outp, N, K);
}

extern "C" void kernel_launch(void* const* d_in, const int* in_sizes, int n_in,
                              void* d_out, int out_size, void* d_ws, size_t ws_size,
                              hipStream_t stream)
{
    const float* x_m0  = (const float*)d_in[0];
    const float* x_m1  = (const float*)d_in[1];
    const float* x_m2  = (const float*)d_in[2];
    const float* Wp_m0 = (const float*)d_in[3];
    const float* bp_m0 = (const float*)d_in[4];
    const float* Wp_m1 = (const float*)d_in[5];
    const float* bp_m1 = (const float*)d_in[6];
    const float* Wp_m2 = (const float*)d_in[7];
    const float* bp_m2 = (const float*)d_in[8];
    const float* Wg    = (const float*)d_in[9];
    const float* bg    = (const float*)d_in[10];
    // d_in[11..14]: Woff/boff/Watt/batt — mathematically dead (Lk==1).
    const float* Wproj = (const float*)d_in[15];
    const float* bproj = (const float*)d_in[16];
    const float* W1    = (const float*)d_in[17];
    const float* b1    = (const float*)d_in[18];
    const float* W2    = (const float*)d_in[19];
    const float* b2    = (const float*)d_in[20];
    const float* g1    = (const float*)d_in[21];
    const float* be1   = (const float*)d_in[22];
    const float* g2    = (const float*)d_in[23];
    const float* be2   = (const float*)d_in[24];
    const float* Wh    = (const float*)d_in[25];
    const float* bh    = (const float*)d_in[26];

    char* ws = (char*)d_ws;
    unsigned short* xb0   = (unsigned short*)(ws + OFF_XB0);
    unsigned short* xb1m  = (unsigned short*)(ws + OFF_XB1M);
    unsigned short* xb2   = (unsigned short*)(ws + OFF_XB2);
    unsigned short* r0    = (unsigned short*)(ws + OFF_R0);
    unsigned short* r1    = (unsigned short*)(ws + OFF_R1);
    unsigned short* r2    = (unsigned short*)(ws + OFF_R2);
    unsigned short* fuseb = (unsigned short*)(ws + OFF_FUSEB);
    float*          fusef = (float*)(ws + OFF_FUSEF);
    float*          z2    = (float*)(ws + OFF_Z2);
    unsigned short* WT0   = (unsigned short*)(ws + OFF_WT0);
    unsigned short* WT1   = (unsigned short*)(ws + OFF_WT1);
    unsigned short* WT2   = (unsigned short*)(ws + OFF_WT2);
    unsigned short* WPT   = (unsigned short*)(ws + OFF_WPT);
    unsigned short* W1T   = (unsigned short*)(ws + OFF_W1T);
    unsigned short* W2T   = (unsigned short*)(ws + OFF_W2T);
    float*          WgT   = (float*)(ws + OFF_WGT);
    float*          WhT   = (float*)(ws + OFF_WHT);
    float*          z1    = (float*)(ws + OFF_Z1);
    unsigned short* h1b   = (unsigned short*)(ws + OFF_H1B);
    float*          h1f   = (float*)(ws + OFF_H1F);
    unsigned short* hmid  = (unsigned short*)(ws + OFF_HMID);
    float*          outp  = (float*)d_out;

    dim3 tb(32, 8);
    // --- weight prep ---
    transpose_k<1><<<dim3(HDIM/32, F0/32), tb, 0, stream>>>(Wp_m0, WT0, F0, HDIM);
    transpose_k<1><<<dim3(HDIM/32, F1/32), tb, 0, stream>>>(Wp_m1, WT1, F1, HDIM);
    transpose_k<1><<<dim3(HDIM/32, F2/32), tb, 0, stream>>>(Wp_m2, WT2, F2, HDIM);
    transpose_k<1><<<dim3(FFDIM/32, HDIM/32), tb, 0, stream>>>(W1, W1T, HDIM, FFDIM);
    transpose_k<1><<<dim3(HDIM/32, FFDIM/32), tb, 0, stream>>>(W2, W2T, FFDIM, HDIM);
    transpose_k<0><<<dim3(1, 3072/32), tb, 0, stream>>>(Wg, WgT, 3072, 3);
    transpose_k<0><<<dim3(1, HDIM/32), tb, 0, stream>>>(Wh, WhT, HDIM, NPRED);
    wproj_sum_k<<<dim3(HDIM/32, HDIM/32), tb, 0, stream>>>(Wproj, WPT);

    // --- activation prep ---
    cvt_f32_bf16_k<<<2048, 256, 0, stream>>>(x_m0, xb0, B_ROWS * F0 / 8);
    cvt_f32_bf16_k<<<2048, 256, 0, stream>>>(x_m2, xb2, B_ROWS * F2 / 8);
    mean8_k<<<2048, 256, 0, stream>>>(x_m1, xb1m, B_ROWS * 256);

    // --- modality projections (relu) ---
    launch_gemm(0, xb0,  WT0, bp_m0, nullptr, r0, B_ROWS, HDIM, F0, stream);
    launch_gemm(0, xb1m, WT1, bp_m1, nullptr, r1, B_ROWS, HDIM, F1, stream);
    launch_gemm(0, xb2,  WT2, bp_m2, nullptr, r2, B_ROWS, HDIM, F2, stream);

    // --- gating + fuse ---
    gating_k<<<B_ROWS / 4, 256, 0, stream>>>(r0, r1, r2, WgT, bg, fuseb, fusef);

    // --- attention-collapsed projection: z1 = fused @ WPT^T + bproj + fused ---
    launch_gemm(2, fuseb, WPT, bproj, fusef, z1, B_ROWS, HDIM, HDIM, stream);

    // --- LN1 ---
    ln_k<<<B_ROWS / 4, 256, 0, stream>>>(z1, g1, be1, h1b, h1f);

    // --- FFN ---
    launch_gemm(1, h1b, W1T, b1, nullptr, hmid, B_ROWS, FFDIM, HDIM, stream);
    launch_gemm(2, hmid, W2T, b2, h1f, z2, B_ROWS, HDIM, FFDIM, stream);

    // --- LN2 + head ---
    head_k<<<B_ROWS / 4, 256, 0, stream>>>(z2, g2, be2, WhT, bh, outp);
}